// Round 16
// baseline (125.028 us; speedup 1.0000x reference)
//
#include <hip/hip_runtime.h>

typedef float f4 __attribute__((ext_vector_type(4)));
typedef float f2 __attribute__((ext_vector_type(2)));
typedef float f32x4 __attribute__((ext_vector_type(4)));
typedef short bf16x8 __attribute__((ext_vector_type(8)));
typedef unsigned short u16x8 __attribute__((ext_vector_type(8)));

__device__ inline unsigned short f2bf(float f) {
  unsigned u = __float_as_uint(f);
  return (unsigned short)((u + 0x7FFF + ((u >> 16) & 1)) >> 16);
}

// prep: 3 weight transposes (f32 -> bf16, WT[c][k]=W[k][c]) + histogram
// (atomic returns rank -> packed into epk.y) + packed edges.
__global__ __launch_bounds__(256) void prep(
    const float* __restrict__ Ws, const float* __restrict__ Wr,
    const float* __restrict__ Wh, const int* __restrict__ edges, int n_edge,
    unsigned short* __restrict__ WsT, unsigned short* __restrict__ WrT,
    unsigned short* __restrict__ WhT, int* __restrict__ counts,
    uint2* __restrict__ epk) {
  const int t = threadIdx.x;
  int b = blockIdx.x;
  if (b < 192) {
    int wsel = b >> 6;
    const float* W = wsel == 0 ? Ws : (wsel == 1 ? Wr : Wh);
    unsigned short* WT = wsel == 0 ? WsT : (wsel == 1 ? WrT : WhT);
    int e = (b & 63) * 256 + t;  // 0..16383
    int cc = e >> 7, kk = e & 127;
    WT[e] = f2bf(W[kk * 128 + cc]);
    return;
  }
  b -= 192;
  int e = b * 256 + t;
  if (e < n_edge) {
    int rel = edges[(size_t)e * 6 + 2];
    int2 so = *(const int2*)(edges + (size_t)e * 6 + 4);  // sub, obj
    unsigned rank = (unsigned)atomicAdd(&counts[so.y], 1);
    epk[e] = make_uint2((unsigned)so.x | ((unsigned)rel << 17),
                        (unsigned)so.y | (rank << 17));
  }
}

// Fused kernel: blocks [0,nbGemm) = dual-output GEMM tiles; blocks
// [nbGemm, nbGemm+NB) = decoupled-lookback scan. Disjoint inputs, both
// ready after prep. Scan blocks publish their aggregate before spinning
// and all fit co-resident -> lookback is deadlock-free in a mixed grid.
__global__ __launch_bounds__(256) void gemm_scan(
    const float* __restrict__ hidden, int M, int nbN,
    const float* __restrict__ rela, int relv,
    const unsigned short* __restrict__ WsT, const unsigned short* __restrict__ WrT,
    const unsigned short* __restrict__ WhT,
    char* __restrict__ rec, char* __restrict__ relrec, int nbGemm,
    const int* __restrict__ counts, int n_edge, int* __restrict__ status,
    int* __restrict__ offsets) {
  __shared__ __align__(16) char lds[81920];  // gemm: A 16K | Wx 32K | Wh 32K
  const int t = threadIdx.x;

  if ((int)blockIdx.x < nbGemm) {
    // ---------------- GEMM path (round-13 measured version) ----------------
    int b = blockIdx.x;
    const float* src;
    const unsigned short* WxT;
    char* out;
    int rows, row0;
    if (b < nbN) { src = hidden; WxT = WsT; out = rec; rows = M; row0 = b * 64; }
    else { src = rela; WxT = WrT; out = relrec; rows = relv; row0 = (b - nbN) * 64; }

#pragma unroll
    for (int i = 0; i < 8; ++i) {
      int m = i * 256 + t;
      int sw = (m * 16) ^ (((m >> 4) & 7) << 4);
      *(u16x8*)(lds + 16384 + sw) = ((const u16x8*)WxT)[m];
      *(u16x8*)(lds + 49152 + sw) = ((const u16x8*)WhT)[m];
    }
#pragma unroll
    for (int i = 0; i < 4; ++i) {
      int m = i * 256 + t;
      int r = m >> 4, c = m & 15;
      int gr = row0 + r;
      if (gr > rows - 1) gr = rows - 1;
      const float* s = src + (size_t)gr * 128 + c * 8;
      f4 lo = *(const f4*)s, hi = *(const f4*)(s + 4);
      u16x8 v;
      v[0] = f2bf(lo.x); v[1] = f2bf(lo.y); v[2] = f2bf(lo.z); v[3] = f2bf(lo.w);
      v[4] = f2bf(hi.x); v[5] = f2bf(hi.y); v[6] = f2bf(hi.z); v[7] = f2bf(hi.w);
      *(u16x8*)(lds + ((m * 16) ^ ((r & 7) << 4))) = v;
    }
    __syncthreads();

    const int w = t >> 6, l = t & 63, lr = l & 15, lg = l >> 4;
    const int rowA = w * 16 + lr;
    bf16x8 afr[4];
#pragma unroll
    for (int k0 = 0; k0 < 4; ++k0)
      afr[k0] = *(const bf16x8*)(lds + rowA * 256 +
                                 ((k0 * 64 + lg * 16) ^ ((rowA & 7) << 4)));

    // pass 1: Wx -> fp8
    {
      f32x4 acc[8] = {};
#pragma unroll
      for (int k0 = 0; k0 < 4; ++k0) {
        int kb = k0 * 64 + lg * 16;
#pragma unroll
        for (int c0 = 0; c0 < 8; ++c0) {
          int cr = c0 * 16 + lr;
          bf16x8 bfr = *(const bf16x8*)(lds + 16384 + cr * 256 + (kb ^ ((cr & 7) << 4)));
          acc[c0] = __builtin_amdgcn_mfma_f32_16x16x32_bf16(afr[k0], bfr, acc[c0], 0, 0, 0);
        }
      }
      __syncthreads();
#pragma unroll
      for (int c0 = 0; c0 < 8; ++c0) {
        int col = c0 * 16 + lr;
#pragma unroll
        for (int j = 0; j < 4; ++j) {
          int row = w * 16 + lg * 4 + j;
          unsigned pk = __builtin_amdgcn_cvt_pk_fp8_f32(acc[c0][j], acc[c0][j], 0, false);
          *(unsigned char*)(lds + 16384 + row * 128 + col) = (unsigned char)pk;
        }
      }
      __syncthreads();
#pragma unroll
      for (int it = 0; it < 2; ++it) {
        int idx = it * 256 + t;
        int row = idx >> 3, seg = idx & 7;
        int grow = row0 + row;
        if (grow < rows) {
          uint4 v = *(const uint4*)(lds + 16384 + row * 128 + seg * 16);
          *(uint4*)(out + (size_t)grow * 384 + 256 + seg * 16) = v;
        }
      }
    }
    __syncthreads();
    // pass 2: Wh -> bf16
    {
      f32x4 acc[8] = {};
#pragma unroll
      for (int k0 = 0; k0 < 4; ++k0) {
        int kb = k0 * 64 + lg * 16;
#pragma unroll
        for (int c0 = 0; c0 < 8; ++c0) {
          int cr = c0 * 16 + lr;
          bf16x8 bfr = *(const bf16x8*)(lds + 49152 + cr * 256 + (kb ^ ((cr & 7) << 4)));
          acc[c0] = __builtin_amdgcn_mfma_f32_16x16x32_bf16(afr[k0], bfr, acc[c0], 0, 0, 0);
        }
      }
      __syncthreads();
#pragma unroll
      for (int c0 = 0; c0 < 8; ++c0) {
        int col = c0 * 16 + lr;
#pragma unroll
        for (int j = 0; j < 4; ++j) {
          int row = w * 16 + lg * 4 + j;
          *(unsigned short*)(lds + 16384 + row * 256 + col * 2) = f2bf(acc[c0][j]);
        }
      }
      __syncthreads();
#pragma unroll
      for (int it = 0; it < 4; ++it) {
        int idx = it * 256 + t;
        int row = idx >> 4, seg = idx & 15;
        int grow = row0 + row;
        if (grow < rows) {
          uint4 v = *(const uint4*)(lds + 16384 + row * 256 + seg * 16);
          *(uint4*)(out + (size_t)grow * 384 + seg * 16) = v;
        }
      }
    }
    return;
  }

  // ---------------- scan path (decoupled lookback) ----------------
  const int b = (int)blockIdx.x - nbGemm;
  const int idx = b * 256 + t;
  int c = (idx < M) ? counts[idx] : 0;
  const int lane = t & 63, w = t >> 6;
  int s = c;
  for (int off = 1; off < 64; off <<= 1) {
    int o = __shfl_up(s, off, 64);
    if (lane >= off) s += o;
  }
  __shared__ int wsum[4], wpre[4];
  __shared__ int blk_prefix;
  if (lane == 63) wsum[w] = s;
  __syncthreads();
  if (t == 0) {
    int r = 0;
#pragma unroll
    for (int i = 0; i < 4; ++i) { wpre[i] = r; r += wsum[i]; }
    unsigned pub = ((b == 0 ? 2u : 1u) << 30) | (unsigned)r;
    __hip_atomic_store(&status[b], (int)pub, __ATOMIC_RELEASE, __HIP_MEMORY_SCOPE_AGENT);
    if (b == 0) blk_prefix = 0;
  }
  __syncthreads();
  if (b > 0 && w == 0) {
    int prefix = 0;
    int k = b - 1;
    for (;;) {
      int j = k - lane;
      unsigned v;
      if (j >= 0) {
        do {
          v = (unsigned)__hip_atomic_load(&status[j], __ATOMIC_ACQUIRE,
                                          __HIP_MEMORY_SCOPE_AGENT);
        } while ((v >> 30) == 0u);
      } else {
        v = 2u << 30;
      }
      int val = (int)(v & 0x3FFFFFFFu);
      unsigned long long incl = __ballot((v >> 30) == 2u);
      int l = (int)__ffsll(incl) - 1;
      int contrib = (l >= 0) ? ((lane <= l) ? val : 0) : val;
#pragma unroll
      for (int off = 32; off; off >>= 1) contrib += __shfl_xor(contrib, off, 64);
      prefix += contrib;
      if (l >= 0) break;
      k -= 64;
    }
    if (lane == 0) {
      blk_prefix = prefix;
      int total = wpre[3] + wsum[3];
      __hip_atomic_store(&status[b], (int)((2u << 30) | (unsigned)(prefix + total)),
                         __ATOMIC_RELEASE, __HIP_MEMORY_SCOPE_AGENT);
    }
  }
  __syncthreads();
  int excl = blk_prefix + wpre[w] + s - c;
  if (idx < M) offsets[idx] = excl;
  if (idx == 0) offsets[M] = n_edge;
}

// Atomic-free CSR placement: slot = offsets[obj] + rank (rank from prep).
__global__ __launch_bounds__(256) void placement_kernel(const uint2* __restrict__ epk,
                                                        int n_edge,
                                                        const int* __restrict__ offsets,
                                                        unsigned* __restrict__ esr) {
  int e = blockIdx.x * 256 + threadIdx.x;
  if (e < n_edge) {
    uint2 pe = epk[e];
    unsigned obj = pe.y & 0x1FFFFu, rank = pe.y >> 17;
    esr[offsets[obj] + rank] = pe.x;
  }
}

template <bool HI>
__device__ inline f2 pk8(unsigned u) {
  return __builtin_amdgcn_cvt_pk_f32_fp8(u, HI);
}

__device__ inline float edge_alpha(uint2 as, uint2 ar, const f2* wap, float bb) {
  f2 s0 = pk8<false>(as.x) + pk8<false>(ar.x);
  f2 s1 = pk8<true>(as.x) + pk8<true>(ar.x);
  f2 s2 = pk8<false>(as.y) + pk8<false>(ar.y);
  f2 s3 = pk8<true>(as.y) + pk8<true>(ar.y);
  s0.x = fmaxf(s0.x, 0.f); s0.y = fmaxf(s0.y, 0.f);
  s1.x = fmaxf(s1.x, 0.f); s1.y = fmaxf(s1.y, 0.f);
  s2.x = fmaxf(s2.x, 0.f); s2.y = fmaxf(s2.y, 0.f);
  s3.x = fmaxf(s3.x, 0.f); s3.y = fmaxf(s3.y, 0.f);
  f2 pp = s0 * wap[0];
  pp += s1 * wap[1];
  pp += s2 * wap[2];
  pp += s3 * wap[3];
  float p = pp.x + pp.y;
#pragma unroll
  for (int off = 1; off <= 8; off <<= 1) p += __shfl_xor(p, off, 64);
  return __builtin_amdgcn_rcpf(1.f + __builtin_amdgcn_exp2f(-(p + bb)));
}

// Wave = 1 node; 4x16-lane groups own interleaved edges (stride 8, unroll x2):
// 8 edge gather-sets in flight per wave, tail masked via alpha=0.
__global__ __launch_bounds__(256) void node_agg(
    const int* __restrict__ offsets, const unsigned* __restrict__ esr,
    const char* __restrict__ rec, const char* __restrict__ relrec,
    float* __restrict__ out,
    const float* __restrict__ w_alpha, const float* __restrict__ w_b, int M) {
  const int lane = threadIdx.x & 63;
  const int g = lane >> 4, gl = lane & 15;
  const int n = (int)((blockIdx.x * 256u + threadIdx.x) >> 6);
  if (n >= M) return;
  const unsigned bH = gl * 16u, bA = 256u + gl * 8u;
  const float LOG2E = 1.44269504f;
  f2 wap[4];
#pragma unroll
  for (int k = 0; k < 4; ++k) wap[k] = ((const f2*)w_alpha)[gl * 4 + k] * LOG2E;
  const float bb = w_b[0] * LOG2E;

  const int beg = offsets[n], end = offsets[n + 1];
  f2 acc2[4] = {};

  for (int i = beg + g; i < end; i += 8) {
    const bool has2 = (i + 4) < end;
    unsigned u1 = esr[i];
    unsigned u2 = has2 ? esr[i + 4] : u1;
    unsigned o1x = (u1 & 0x1FFFFu) * 384u, o1y = (u1 >> 17) * 384u;
    unsigned o2x = (u2 & 0x1FFFFu) * 384u, o2y = (u2 >> 17) * 384u;

    u16x8 h1 = *(const u16x8*)(rec + o1x + bH);
    uint2 as1 = *(const uint2*)(rec + o1x + bA);
    u16x8 r1 = *(const u16x8*)(relrec + o1y + bH);
    uint2 ar1 = *(const uint2*)(relrec + o1y + bA);
    u16x8 h2 = *(const u16x8*)(rec + o2x + bH);
    uint2 as2 = *(const uint2*)(rec + o2x + bA);
    u16x8 r2 = *(const u16x8*)(relrec + o2y + bH);
    uint2 ar2 = *(const uint2*)(relrec + o2y + bA);

    float al1 = edge_alpha(as1, ar1, wap, bb);
    float al2 = edge_alpha(as2, ar2, wap, bb);
    if (!has2) al2 = 0.f;

    const uint4 hu1 = *(const uint4*)&h1, ru1 = *(const uint4*)&r1;
    const uint4 hu2 = *(const uint4*)&h2, ru2 = *(const uint4*)&r2;
    const unsigned hd1[4] = {hu1.x, hu1.y, hu1.z, hu1.w};
    const unsigned rd1[4] = {ru1.x, ru1.y, ru1.z, ru1.w};
    const unsigned hd2[4] = {hu2.x, hu2.y, hu2.z, hu2.w};
    const unsigned rd2[4] = {ru2.x, ru2.y, ru2.z, ru2.w};
#pragma unroll
    for (int k = 0; k < 4; ++k) {
      f2 m1, m2;
      m1.x = __uint_as_float(hd1[k] << 16) + __uint_as_float(rd1[k] << 16);
      m1.y = __uint_as_float(hd1[k] & 0xFFFF0000u) + __uint_as_float(rd1[k] & 0xFFFF0000u);
      m2.x = __uint_as_float(hd2[k] << 16) + __uint_as_float(rd2[k] << 16);
      m2.y = __uint_as_float(hd2[k] & 0xFFFF0000u) + __uint_as_float(rd2[k] & 0xFFFF0000u);
      acc2[k] += al1 * m1;
      acc2[k] += al2 * m2;
    }
  }

#pragma unroll
  for (int k = 0; k < 4; ++k) {
    acc2[k].x += __shfl_xor(acc2[k].x, 16, 64);
    acc2[k].y += __shfl_xor(acc2[k].y, 16, 64);
    acc2[k].x += __shfl_xor(acc2[k].x, 32, 64);
    acc2[k].y += __shfl_xor(acc2[k].y, 32, 64);
  }
  if (g == 0) {
    f4 lo = {acc2[0].x, acc2[0].y, acc2[1].x, acc2[1].y};
    f4 hi = {acc2[2].x, acc2[2].y, acc2[3].x, acc2[3].y};
    float* dst = out + (size_t)n * 128 + gl * 8;
    *(f4*)dst = lo;
    *(f4*)(dst + 4) = hi;
  }
}

extern "C" void kernel_launch(void* const* d_in, const int* in_sizes, int n_in,
                              void* d_out, int out_size, void* d_ws, size_t ws_size,
                              hipStream_t stream) {
  const float* hidden = (const float*)d_in[0];
  const int* edges = (const int*)d_in[1];
  const float* rela = (const float*)d_in[4];
  const float* Ws = (const float*)d_in[5];
  const float* Wr = (const float*)d_in[6];
  const float* wa = (const float*)d_in[7];
  const float* wb = (const float*)d_in[8];
  const float* Wh = (const float*)d_in[9];

  const int M = in_sizes[0] / 128;     // 50000
  const int n_edge = in_sizes[1] / 6;  // 640000
  const int relv = in_sizes[4] / 128;  // 1003
  const int NB = (M + 255) / 256;
  const int BE = (n_edge + 255) / 256;

  char* ws = (char*)d_ws;
  size_t off = 0;
  char* rec = ws; off += ((size_t)M * 384 + 255) & ~255ull;
  char* relrec = ws + off; off += ((size_t)relv * 384 + 255) & ~255ull;
  unsigned short* WsT = (unsigned short*)(ws + off); off += 32768;
  unsigned short* WrT = (unsigned short*)(ws + off); off += 32768;
  unsigned short* WhT = (unsigned short*)(ws + off); off += 32768;
  unsigned* esr = (unsigned*)(ws + off); off += ((size_t)n_edge * 4 + 255) & ~255ull;
  uint2* epk = (uint2*)(ws + off); off += (size_t)n_edge * 8;
  int* counts = (int*)(ws + off); off += (size_t)M * 4;
  int* status = (int*)(ws + off); off += 4096;
  int* offsets = (int*)(ws + off); off += ((size_t)(M + 1) * 4 + 255) & ~255ull;
  float* out = (float*)d_out;

  (void)hipMemsetAsync(counts, 0, (size_t)M * 4 + 4096, stream);

  prep<<<192 + BE, 256, 0, stream>>>(Ws, Wr, Wh, edges, n_edge, WsT, WrT, WhT,
                                     counts, epk);

  const int nbN = (M + 63) / 64;
  const int nbGemm = nbN + (relv + 63) / 64;
  gemm_scan<<<nbGemm + NB, 256, 0, stream>>>(hidden, M, nbN, rela, relv,
                                             WsT, WrT, WhT, rec, relrec, nbGemm,
                                             counts, n_edge, status, offsets);

  placement_kernel<<<BE, 256, 0, stream>>>(epk, n_edge, offsets, esr);

  node_agg<<<(M * 64 + 255) / 256, 256, 0, stream>>>(offsets, esr, rec, relrec,
                                                     out, wa, wb, M);
}

// Round 17
// 122.547 us; speedup vs baseline: 1.0202x; 1.0202x over previous
//
#include <hip/hip_runtime.h>

typedef float f4 __attribute__((ext_vector_type(4)));
typedef float f2 __attribute__((ext_vector_type(2)));
typedef float f32x4 __attribute__((ext_vector_type(4)));
typedef short bf16x8 __attribute__((ext_vector_type(8)));
typedef unsigned short u16x8 __attribute__((ext_vector_type(8)));

__device__ inline unsigned short f2bf(float f) {
  unsigned u = __float_as_uint(f);
  return (unsigned short)((u + 0x7FFF + ((u >> 16) & 1)) >> 16);
}

// prep: 3 weight transposes (f32 -> bf16, WT[c][k]=W[k][c]) + histogram
// (atomic returns rank -> packed into epk.y) + packed edges.
__global__ __launch_bounds__(256) void prep(
    const float* __restrict__ Ws, const float* __restrict__ Wr,
    const float* __restrict__ Wh, const int* __restrict__ edges, int n_edge,
    unsigned short* __restrict__ WsT, unsigned short* __restrict__ WrT,
    unsigned short* __restrict__ WhT, int* __restrict__ counts,
    uint2* __restrict__ epk) {
  const int t = threadIdx.x;
  int b = blockIdx.x;
  if (b < 192) {
    int wsel = b >> 6;
    const float* W = wsel == 0 ? Ws : (wsel == 1 ? Wr : Wh);
    unsigned short* WT = wsel == 0 ? WsT : (wsel == 1 ? WrT : WhT);
    int e = (b & 63) * 256 + t;  // 0..16383
    int cc = e >> 7, kk = e & 127;
    WT[e] = f2bf(W[kk * 128 + cc]);
    return;
  }
  b -= 192;
  int e = b * 256 + t;
  if (e < n_edge) {
    int rel = edges[(size_t)e * 6 + 2];
    int2 so = *(const int2*)(edges + (size_t)e * 6 + 4);  // sub, obj
    unsigned rank = (unsigned)atomicAdd(&counts[so.y], 1);
    epk[e] = make_uint2((unsigned)so.x | ((unsigned)rel << 17),
                        (unsigned)so.y | (rank << 17));
  }
}

// Dual-output GEMM per 64-row f32 tile (round-13 measured version). Two MFMA
// passes (Wx->fp8, Wh->bf16), epilogue staged through LDS for coalesced stores.
__global__ __launch_bounds__(256) void gemm_dual(
    const float* __restrict__ hidden, int M, int nbN,
    const float* __restrict__ rela, int relv,
    const unsigned short* __restrict__ WsT, const unsigned short* __restrict__ WrT,
    const unsigned short* __restrict__ WhT,
    char* __restrict__ rec, char* __restrict__ relrec) {
  __shared__ __align__(16) char lds[81920];  // A 16K | Wx 32K | Wh 32K
  const int t = threadIdx.x;
  int b = blockIdx.x;
  const float* src;
  const unsigned short* WxT;
  char* out;
  int rows, row0;
  if (b < nbN) { src = hidden; WxT = WsT; out = rec; rows = M; row0 = b * 64; }
  else { src = rela; WxT = WrT; out = relrec; rows = relv; row0 = (b - nbN) * 64; }

#pragma unroll
  for (int i = 0; i < 8; ++i) {
    int m = i * 256 + t;
    int sw = (m * 16) ^ (((m >> 4) & 7) << 4);
    *(u16x8*)(lds + 16384 + sw) = ((const u16x8*)WxT)[m];
    *(u16x8*)(lds + 49152 + sw) = ((const u16x8*)WhT)[m];
  }
#pragma unroll
  for (int i = 0; i < 4; ++i) {
    int m = i * 256 + t;
    int r = m >> 4, c = m & 15;
    int gr = row0 + r;
    if (gr > rows - 1) gr = rows - 1;
    const float* s = src + (size_t)gr * 128 + c * 8;
    f4 lo = *(const f4*)s, hi = *(const f4*)(s + 4);
    u16x8 v;
    v[0] = f2bf(lo.x); v[1] = f2bf(lo.y); v[2] = f2bf(lo.z); v[3] = f2bf(lo.w);
    v[4] = f2bf(hi.x); v[5] = f2bf(hi.y); v[6] = f2bf(hi.z); v[7] = f2bf(hi.w);
    *(u16x8*)(lds + ((m * 16) ^ ((r & 7) << 4))) = v;
  }
  __syncthreads();

  const int w = t >> 6, l = t & 63, lr = l & 15, lg = l >> 4;
  const int rowA = w * 16 + lr;
  bf16x8 afr[4];
#pragma unroll
  for (int k0 = 0; k0 < 4; ++k0)
    afr[k0] = *(const bf16x8*)(lds + rowA * 256 + ((k0 * 64 + lg * 16) ^ ((rowA & 7) << 4)));

  // pass 1: Wx -> fp8
  {
    f32x4 acc[8] = {};
#pragma unroll
    for (int k0 = 0; k0 < 4; ++k0) {
      int kb = k0 * 64 + lg * 16;
#pragma unroll
      for (int c0 = 0; c0 < 8; ++c0) {
        int cr = c0 * 16 + lr;
        bf16x8 bfr = *(const bf16x8*)(lds + 16384 + cr * 256 + (kb ^ ((cr & 7) << 4)));
        acc[c0] = __builtin_amdgcn_mfma_f32_16x16x32_bf16(afr[k0], bfr, acc[c0], 0, 0, 0);
      }
    }
    __syncthreads();  // all Wx LDS reads done; region reusable
#pragma unroll
    for (int c0 = 0; c0 < 8; ++c0) {
      int col = c0 * 16 + lr;
#pragma unroll
      for (int j = 0; j < 4; ++j) {
        int row = w * 16 + lg * 4 + j;
        unsigned pk = __builtin_amdgcn_cvt_pk_fp8_f32(acc[c0][j], acc[c0][j], 0, false);
        *(unsigned char*)(lds + 16384 + row * 128 + col) = (unsigned char)pk;
      }
    }
    __syncthreads();
    // coalesced store: 64 rows x 128B
#pragma unroll
    for (int it = 0; it < 2; ++it) {
      int idx = it * 256 + t;
      int row = idx >> 3, seg = idx & 7;
      int grow = row0 + row;
      if (grow < rows) {
        uint4 v = *(const uint4*)(lds + 16384 + row * 128 + seg * 16);
        *(uint4*)(out + (size_t)grow * 384 + 256 + seg * 16) = v;
      }
    }
  }
  __syncthreads();
  // pass 2: Wh -> bf16
  {
    f32x4 acc[8] = {};
#pragma unroll
    for (int k0 = 0; k0 < 4; ++k0) {
      int kb = k0 * 64 + lg * 16;
#pragma unroll
      for (int c0 = 0; c0 < 8; ++c0) {
        int cr = c0 * 16 + lr;
        bf16x8 bfr = *(const bf16x8*)(lds + 49152 + cr * 256 + (kb ^ ((cr & 7) << 4)));
        acc[c0] = __builtin_amdgcn_mfma_f32_16x16x32_bf16(afr[k0], bfr, acc[c0], 0, 0, 0);
      }
    }
    __syncthreads();
#pragma unroll
    for (int c0 = 0; c0 < 8; ++c0) {
      int col = c0 * 16 + lr;
#pragma unroll
      for (int j = 0; j < 4; ++j) {
        int row = w * 16 + lg * 4 + j;
        *(unsigned short*)(lds + 16384 + row * 256 + col * 2) = f2bf(acc[c0][j]);
      }
    }
    __syncthreads();
    // coalesced store: 64 rows x 256B
#pragma unroll
    for (int it = 0; it < 4; ++it) {
      int idx = it * 256 + t;
      int row = idx >> 4, seg = idx & 15;
      int grow = row0 + row;
      if (grow < rows) {
        uint4 v = *(const uint4*)(lds + 16384 + row * 256 + seg * 16);
        *(uint4*)(out + (size_t)grow * 384 + seg * 16) = v;
      }
    }
  }
}

// Single-pass exclusive scan, decoupled lookback.
__global__ __launch_bounds__(256) void scan_lookback(
    const int* __restrict__ counts, int M, int n_edge, int* __restrict__ status,
    int* __restrict__ offsets) {
  const int t = threadIdx.x, b = blockIdx.x;
  const int idx = b * 256 + t;
  int c = (idx < M) ? counts[idx] : 0;
  const int lane = t & 63, w = t >> 6;
  int s = c;
  for (int off = 1; off < 64; off <<= 1) {
    int o = __shfl_up(s, off, 64);
    if (lane >= off) s += o;
  }
  __shared__ int wsum[4], wpre[4];
  __shared__ int blk_prefix;
  if (lane == 63) wsum[w] = s;
  __syncthreads();
  if (t == 0) {
    int r = 0;
#pragma unroll
    for (int i = 0; i < 4; ++i) { wpre[i] = r; r += wsum[i]; }
    unsigned pub = ((b == 0 ? 2u : 1u) << 30) | (unsigned)r;
    __hip_atomic_store(&status[b], (int)pub, __ATOMIC_RELEASE, __HIP_MEMORY_SCOPE_AGENT);
    if (b == 0) blk_prefix = 0;
  }
  __syncthreads();
  if (b > 0 && w == 0) {
    int prefix = 0;
    int k = b - 1;
    for (;;) {
      int j = k - lane;
      unsigned v;
      if (j >= 0) {
        do {
          v = (unsigned)__hip_atomic_load(&status[j], __ATOMIC_ACQUIRE,
                                          __HIP_MEMORY_SCOPE_AGENT);
        } while ((v >> 30) == 0u);
      } else {
        v = 2u << 30;
      }
      int val = (int)(v & 0x3FFFFFFFu);
      unsigned long long incl = __ballot((v >> 30) == 2u);
      int l = (int)__ffsll(incl) - 1;
      int contrib = (l >= 0) ? ((lane <= l) ? val : 0) : val;
#pragma unroll
      for (int off = 32; off; off >>= 1) contrib += __shfl_xor(contrib, off, 64);
      prefix += contrib;
      if (l >= 0) break;
      k -= 64;
    }
    if (lane == 0) {
      blk_prefix = prefix;
      int total = wpre[3] + wsum[3];
      __hip_atomic_store(&status[b], (int)((2u << 30) | (unsigned)(prefix + total)),
                         __ATOMIC_RELEASE, __HIP_MEMORY_SCOPE_AGENT);
    }
  }
  __syncthreads();
  int excl = blk_prefix + wpre[w] + s - c;
  if (idx < M) offsets[idx] = excl;
  if (idx == 0) offsets[M] = n_edge;
}

// Atomic-free CSR placement: slot = offsets[obj] + rank (rank from prep).
__global__ __launch_bounds__(256) void placement_kernel(const uint2* __restrict__ epk,
                                                        int n_edge,
                                                        const int* __restrict__ offsets,
                                                        unsigned* __restrict__ esr) {
  int e = blockIdx.x * 256 + threadIdx.x;
  if (e < n_edge) {
    uint2 pe = epk[e];
    unsigned obj = pe.y & 0x1FFFFu, rank = pe.y >> 17;
    esr[offsets[obj] + rank] = pe.x;
  }
}

template <bool HI>
__device__ inline f2 pk8(unsigned u) {
  return __builtin_amdgcn_cvt_pk_f32_fp8(u, HI);
}

__device__ inline float edge_alpha(uint2 as, uint2 ar, const f2* wap, float bb) {
  f2 s0 = pk8<false>(as.x) + pk8<false>(ar.x);
  f2 s1 = pk8<true>(as.x) + pk8<true>(ar.x);
  f2 s2 = pk8<false>(as.y) + pk8<false>(ar.y);
  f2 s3 = pk8<true>(as.y) + pk8<true>(ar.y);
  s0.x = fmaxf(s0.x, 0.f); s0.y = fmaxf(s0.y, 0.f);
  s1.x = fmaxf(s1.x, 0.f); s1.y = fmaxf(s1.y, 0.f);
  s2.x = fmaxf(s2.x, 0.f); s2.y = fmaxf(s2.y, 0.f);
  s3.x = fmaxf(s3.x, 0.f); s3.y = fmaxf(s3.y, 0.f);
  f2 pp = s0 * wap[0];
  pp += s1 * wap[1];
  pp += s2 * wap[2];
  pp += s3 * wap[3];
  float p = pp.x + pp.y;
#pragma unroll
  for (int off = 1; off <= 8; off <<= 1) p += __shfl_xor(p, off, 64);
  return __builtin_amdgcn_rcpf(1.f + __builtin_amdgcn_exp2f(-(p + bb)));
}

// Wave = 1 node; 4x16-lane groups own interleaved edges (stride 8, unroll x2):
// 8 edge gather-sets in flight per wave, tail masked via alpha=0.
__global__ __launch_bounds__(256) void node_agg(
    const int* __restrict__ offsets, const unsigned* __restrict__ esr,
    const char* __restrict__ rec, const char* __restrict__ relrec,
    float* __restrict__ out,
    const float* __restrict__ w_alpha, const float* __restrict__ w_b, int M) {
  const int lane = threadIdx.x & 63;
  const int g = lane >> 4, gl = lane & 15;
  const int n = (int)((blockIdx.x * 256u + threadIdx.x) >> 6);
  if (n >= M) return;
  const unsigned bH = gl * 16u, bA = 256u + gl * 8u;
  const float LOG2E = 1.44269504f;
  f2 wap[4];
#pragma unroll
  for (int k = 0; k < 4; ++k) wap[k] = ((const f2*)w_alpha)[gl * 4 + k] * LOG2E;
  const float bb = w_b[0] * LOG2E;

  const int beg = offsets[n], end = offsets[n + 1];
  f2 acc2[4] = {};

  for (int i = beg + g; i < end; i += 8) {
    const bool has2 = (i + 4) < end;
    unsigned u1 = esr[i];
    unsigned u2 = has2 ? esr[i + 4] : u1;
    unsigned o1x = (u1 & 0x1FFFFu) * 384u, o1y = (u1 >> 17) * 384u;
    unsigned o2x = (u2 & 0x1FFFFu) * 384u, o2y = (u2 >> 17) * 384u;

    u16x8 h1 = *(const u16x8*)(rec + o1x + bH);
    uint2 as1 = *(const uint2*)(rec + o1x + bA);
    u16x8 r1 = *(const u16x8*)(relrec + o1y + bH);
    uint2 ar1 = *(const uint2*)(relrec + o1y + bA);
    u16x8 h2 = *(const u16x8*)(rec + o2x + bH);
    uint2 as2 = *(const uint2*)(rec + o2x + bA);
    u16x8 r2 = *(const u16x8*)(relrec + o2y + bH);
    uint2 ar2 = *(const uint2*)(relrec + o2y + bA);

    float al1 = edge_alpha(as1, ar1, wap, bb);
    float al2 = edge_alpha(as2, ar2, wap, bb);
    if (!has2) al2 = 0.f;

    const uint4 hu1 = *(const uint4*)&h1, ru1 = *(const uint4*)&r1;
    const uint4 hu2 = *(const uint4*)&h2, ru2 = *(const uint4*)&r2;
    const unsigned hd1[4] = {hu1.x, hu1.y, hu1.z, hu1.w};
    const unsigned rd1[4] = {ru1.x, ru1.y, ru1.z, ru1.w};
    const unsigned hd2[4] = {hu2.x, hu2.y, hu2.z, hu2.w};
    const unsigned rd2[4] = {ru2.x, ru2.y, ru2.z, ru2.w};
#pragma unroll
    for (int k = 0; k < 4; ++k) {
      f2 m1, m2;
      m1.x = __uint_as_float(hd1[k] << 16) + __uint_as_float(rd1[k] << 16);
      m1.y = __uint_as_float(hd1[k] & 0xFFFF0000u) + __uint_as_float(rd1[k] & 0xFFFF0000u);
      m2.x = __uint_as_float(hd2[k] << 16) + __uint_as_float(rd2[k] << 16);
      m2.y = __uint_as_float(hd2[k] & 0xFFFF0000u) + __uint_as_float(rd2[k] & 0xFFFF0000u);
      acc2[k] += al1 * m1;
      acc2[k] += al2 * m2;
    }
  }

#pragma unroll
  for (int k = 0; k < 4; ++k) {
    acc2[k].x += __shfl_xor(acc2[k].x, 16, 64);
    acc2[k].y += __shfl_xor(acc2[k].y, 16, 64);
    acc2[k].x += __shfl_xor(acc2[k].x, 32, 64);
    acc2[k].y += __shfl_xor(acc2[k].y, 32, 64);
  }
  if (g == 0) {
    f4 lo = {acc2[0].x, acc2[0].y, acc2[1].x, acc2[1].y};
    f4 hi = {acc2[2].x, acc2[2].y, acc2[3].x, acc2[3].y};
    float* dst = out + (size_t)n * 128 + gl * 8;
    *(f4*)dst = lo;
    *(f4*)(dst + 4) = hi;
  }
}

extern "C" void kernel_launch(void* const* d_in, const int* in_sizes, int n_in,
                              void* d_out, int out_size, void* d_ws, size_t ws_size,
                              hipStream_t stream) {
  const float* hidden = (const float*)d_in[0];
  const int* edges = (const int*)d_in[1];
  const float* rela = (const float*)d_in[4];
  const float* Ws = (const float*)d_in[5];
  const float* Wr = (const float*)d_in[6];
  const float* wa = (const float*)d_in[7];
  const float* wb = (const float*)d_in[8];
  const float* Wh = (const float*)d_in[9];

  const int M = in_sizes[0] / 128;     // 50000
  const int n_edge = in_sizes[1] / 6;  // 640000
  const int relv = in_sizes[4] / 128;  // 1003
  const int NB = (M + 255) / 256;
  const int BE = (n_edge + 255) / 256;

  char* ws = (char*)d_ws;
  size_t off = 0;
  char* rec = ws; off += ((size_t)M * 384 + 255) & ~255ull;
  char* relrec = ws + off; off += ((size_t)relv * 384 + 255) & ~255ull;
  unsigned short* WsT = (unsigned short*)(ws + off); off += 32768;
  unsigned short* WrT = (unsigned short*)(ws + off); off += 32768;
  unsigned short* WhT = (unsigned short*)(ws + off); off += 32768;
  unsigned* esr = (unsigned*)(ws + off); off += ((size_t)n_edge * 4 + 255) & ~255ull;
  uint2* epk = (uint2*)(ws + off); off += (size_t)n_edge * 8;
  int* counts = (int*)(ws + off); off += (size_t)M * 4;
  int* status = (int*)(ws + off); off += 4096;
  int* offsets = (int*)(ws + off); off += ((size_t)(M + 1) * 4 + 255) & ~255ull;
  float* out = (float*)d_out;

  (void)hipMemsetAsync(counts, 0, (size_t)M * 4 + 4096, stream);

  prep<<<192 + BE, 256, 0, stream>>>(Ws, Wr, Wh, edges, n_edge, WsT, WrT, WhT,
                                     counts, epk);

  const int nbN = (M + 63) / 64;
  gemm_dual<<<nbN + (relv + 63) / 64, 256, 0, stream>>>(hidden, M, nbN, rela, relv,
                                                        WsT, WrT, WhT, rec, relrec);

  scan_lookback<<<NB, 256, 0, stream>>>(counts, M, n_edge, status, offsets);
  placement_kernel<<<BE, 256, 0, stream>>>(epk, n_edge, offsets, esr);

  node_agg<<<(M * 64 + 255) / 256, 256, 0, stream>>>(offsets, esr, rec, relrec,
                                                     out, wa, wb, M);
}